// Round 8
// baseline (497.136 us; speedup 1.0000x reference)
//
#include <hip/hip_runtime.h>
#include <cstddef>

// ---------------------------------------------------------------------------
// CNN1D_LSTM1 pipeline, round 17: single-wave register-resident LSTM
//   prep:   conv1 effective-weight pack (bf16 B-fragments) + b_eff
//   conv1p: conv 16->32 k30 MFMA + fused maxpool(k20,s5,ceil) -> S2b bf16
//   conv2:  conv 32->64 k10 MFMA (self-packs weights) -> S3 fp32
//   branch: adaptive maxpool + conv(64->4,k3,p1)+leaky + Xg store
//           (Xg re-laid: per (t,bt) each lane's 16 gate floats contiguous)
//   lstm:   ONE wave per 4-batch tile computes all 256 gate cols itself:
//           W_hh in 128 VGPRs, 32 MFMA/step, h redistributed via 16
//           ds_bpermute (intra-wave lockstep: NO barrier, NO LDS, NO
//           waitcnt in the recurrence).  Garbage A-rows harmless (C row r
//           depends only on A row r; only rows {0,4,8,12} are read).
//           grid (16 bt, 2 br) = 32 blocks x 64 thr.
// ---------------------------------------------------------------------------

typedef __attribute__((ext_vector_type(8))) short bf16x8;
typedef __attribute__((ext_vector_type(4))) float f32x4;
typedef __attribute__((ext_vector_type(4))) unsigned int u32x4;
typedef unsigned int uint32;

#define LOG2E 1.4426950408889634f

__device__ __forceinline__ unsigned short f2bf(float f) {
    unsigned u = __float_as_uint(f);
    u += 0x7fffu + ((u >> 16) & 1u);   // RNE
    return (unsigned short)(u >> 16);
}
__device__ __forceinline__ float bf2f(unsigned short h) {
    return __uint_as_float(((unsigned)h) << 16);
}
__device__ __forceinline__ float exp2_(float x) {
#if __has_builtin(__builtin_amdgcn_exp2f)
    return __builtin_amdgcn_exp2f(x);
#else
    return __expf(0.6931471805599453f * x);
#endif
}
// rcp2(x) = 1/(1+2^x).  With x pre-scaled by -log2e: == sigmoid(a).
__device__ __forceinline__ float rcp2(float x) {
    return __builtin_amdgcn_rcpf(1.0f + exp2_(x));
}
__device__ __forceinline__ float sigm(float x) {
    return __builtin_amdgcn_rcpf(1.0f + __expf(-x));
}
__device__ __forceinline__ float leaky(float v) { return v >= 0.0f ? v : 0.01f * v; }

// ---------------------------------------------------------------------------
// prep: Wp1[(kc*32+n)*32 + k'] = w_eff(ch=k'&15, kappa=2kc+(k'>>4), o=n); b_eff
__global__ void prep_kernel(const float* __restrict__ w_dw, const float* __restrict__ b_dw,
                            const float* __restrict__ w_pw, const float* __restrict__ b_pw,
                            unsigned short* __restrict__ Wp1, float* __restrict__ b_eff) {
    const int bid = blockIdx.x, tid = threadIdx.x;
    if (bid < 15) {
        const int kc = bid;
        for (int it = 0; it < 4; ++it) {
            int idx = tid + it * 256;
            int n = idx >> 5, kp = idx & 31;
            int ch = kp & 15, kappa = kc * 2 + (kp >> 4);
            float s = 0.f;
            for (int j = 0; j < 16; ++j)
                s += w_pw[n * 256 + ch * 16 + j] * w_dw[(ch * 16 + j) * 30 + kappa];
            Wp1[(kc * 32 + n) * 32 + kp] = f2bf(s);
        }
    } else if (tid < 32) {
        float s = b_pw[tid];
        for (int c = 0; c < 256; ++c) s += w_pw[tid * 256 + c] * b_dw[c];
        b_eff[tid] = s;
    }
}

// ---------------------------------------------------------------------------
// conv1p: grid (26 ttiles, 64 b), 256 thr.  Tile = 32 pool outputs.
__global__ __launch_bounds__(256) void conv1p_kernel(const float* __restrict__ X,
        const unsigned short* __restrict__ Wp1, const float* __restrict__ b_eff,
        unsigned short* __restrict__ S2b, int* __restrict__ cnt) {
    const int b = blockIdx.y, tx = blockIdx.x, tid = threadIdx.x;
    if (tx == 0 && b == 0 && tid == 0) *cnt = 0;   // reset lstm completion counter
    const int l0 = tx * 160;
    __shared__ __align__(16) unsigned short Wl[480 * 40];  // B-frags, rows padded
    __shared__ __align__(16) unsigned short U[192 * 33];   // Xt[224*24] then Ct[192*33]
    unsigned short* Xt = U;
    {   // stage weights: 1920 int4 (rows 16 dw -> padded 20, 16B-aligned)
        const int4* s4 = (const int4*)Wp1;
        for (int j = tid; j < 1920; j += 256)
            *(int4*)((uint32*)Wl + (j >> 2) * 20 + (j & 3) * 4) = s4[j];
    }
    // stage X transposed bf16, float4 global loads
    for (int i = tid; i < 896; i += 256) {
        int ch = i / 56, p4 = (i - ch * 56) * 4;
        int l = l0 + p4;
        float4 v = {0.f, 0.f, 0.f, 0.f};
        const float* xrow = X + ((size_t)b * 16 + ch) * 4096;
        if (l + 3 < 4096 && p4 + 3 < 221) {
            v = *(const float4*)(xrow + l);
        } else {
            float* vv = (float*)&v;
#pragma unroll
            for (int e = 0; e < 4; ++e) {
                int p = p4 + e, le = l + e;
                vv[e] = (p < 221 && le < 4096) ? xrow[le] : 0.f;
            }
        }
        unsigned short* dst = Xt + p4 * 24 + ch;
        dst[0] = f2bf(v.x); dst[24] = f2bf(v.y); dst[48] = f2bf(v.z); dst[72] = f2bf(v.w);
    }
    __syncthreads();
    const int w = tid >> 6, lane = tid & 63, quad = lane >> 4, l16 = lane & 15;
    const int ki = quad >> 1, ch0 = (quad & 1) * 8;
    f32x4 acc[3][2];
#pragma unroll
    for (int mi = 0; mi < 3; ++mi)
#pragma unroll
        for (int nt = 0; nt < 2; ++nt) acc[mi][nt] = (f32x4){0.f, 0.f, 0.f, 0.f};
#pragma unroll
    for (int kc = 0; kc < 15; ++kc) {
        bf16x8 B0 = *(const bf16x8*)(Wl + (kc * 32 + l16) * 40 + quad * 8);
        bf16x8 B1 = *(const bf16x8*)(Wl + (kc * 32 + 16 + l16) * 40 + quad * 8);
#pragma unroll
        for (int mi = 0; mi < 3; ++mi) {
            int mrow = (w + mi * 4) * 16 + l16 + 2 * kc + ki;
            bf16x8 A = *(const bf16x8*)(Xt + mrow * 24 + ch0);
            acc[mi][0] = __builtin_amdgcn_mfma_f32_16x16x32_bf16(A, B0, acc[mi][0], 0, 0, 0);
            acc[mi][1] = __builtin_amdgcn_mfma_f32_16x16x32_bf16(A, B1, acc[mi][1], 0, 0, 0);
        }
    }
    __syncthreads();                 // all Xt reads done; reuse U as Ct
    unsigned short* Ct = U;          // [192][33]
#pragma unroll
    for (int mi = 0; mi < 3; ++mi) {
        int lrow = (w + mi * 4) * 16 + quad * 4;
#pragma unroll
        for (int nt = 0; nt < 2; ++nt) {
            int o = nt * 16 + l16;
            float be = b_eff[o];
#pragma unroll
            for (int r = 0; r < 4; ++r)
                Ct[(lrow + r) * 33 + o] = f2bf(leaky(acc[mi][nt][r] + be));
        }
    }
    __syncthreads();
    for (int idx = tid; idx < 1024; idx += 256) {    // 32 t x 32 ch
        int ti = idx >> 5, ch = idx & 31;
        int t = tx * 32 + ti;
        if (t < 811) {
            int pmax = 4067 - 5 * t; if (pmax > 20) pmax = 20;   // ceil_mode clamp
            int pbase = 5 * ti;
            float m = bf2f(Ct[pbase * 33 + ch]);
            for (int p = 1; p < pmax; ++p) m = fmaxf(m, bf2f(Ct[(pbase + p) * 33 + ch]));
            S2b[((size_t)b * 32 + ch) * 812 + t] = f2bf(m);
        }
    }
}

// ---------------------------------------------------------------------------
// conv2: grid (13 ltiles, 64 b).  M=64, N=64, K=320; self-packs weights.
__global__ __launch_bounds__(256) void conv2_kernel(const unsigned short* __restrict__ S2b,
        const float* __restrict__ w_c2, const float* __restrict__ b_c2,
        float* __restrict__ S3) {
    const int b = blockIdx.y, l0 = blockIdx.x * 64, tid = threadIdx.x;
    __shared__ __align__(16) unsigned short At[80 * 40];
    __shared__ __align__(16) unsigned short Wl[10 * 64 * 40];
    for (int pair = tid; pair < 2048; pair += 256) {   // (n, kp=ch) pairs
        int n = pair >> 5, kp = pair & 31;
        const float* src = w_c2 + n * 320 + kp * 10;
        unsigned short* dstc = Wl + n * 40 + kp;
#pragma unroll
        for (int kc = 0; kc < 10; ++kc) dstc[kc * 2560] = f2bf(src[kc]);
    }
    for (int i = tid; i < 2560; i += 256) {
        int ch = i / 80, p = i - ch * 80;
        int l = l0 + p;
        At[p * 40 + ch] = (p < 73 && l < 811)
            ? S2b[((size_t)b * 32 + ch) * 812 + l] : (unsigned short)0;
    }
    __syncthreads();
    const int w = tid >> 6, lane = tid & 63, quad = lane >> 4, l16 = lane & 15;
    const int mA = w * 16 + l16, ch0 = quad * 8;
    f32x4 acc[4];
#pragma unroll
    for (int nt = 0; nt < 4; ++nt) acc[nt] = (f32x4){0.f, 0.f, 0.f, 0.f};
#pragma unroll
    for (int kc = 0; kc < 10; ++kc) {
        bf16x8 A = *(const bf16x8*)(At + (mA + kc) * 40 + ch0);
#pragma unroll
        for (int nt = 0; nt < 4; ++nt) {
            bf16x8 Bf = *(const bf16x8*)(Wl + (kc * 64 + nt * 16 + l16) * 40 + quad * 8);
            acc[nt] = __builtin_amdgcn_mfma_f32_16x16x32_bf16(A, Bf, acc[nt], 0, 0, 0);
        }
    }
    const int lbase = l0 + w * 16 + quad * 4;
#pragma unroll
    for (int nt = 0; nt < 4; ++nt) {
        int o = nt * 16 + l16;
        float bc = b_c2[o];
#pragma unroll
        for (int r = 0; r < 4; ++r) {
            int l = lbase + r;
            if (l < 802) S3[((size_t)b * 64 + o) * 802 + l] = leaky(acc[nt][r] + bc);
        }
    }
}

// ---------------------------------------------------------------------------
// branch: adaptive maxpool + conv(64->4,k3,p1)+leaky + Xg precompute+store.
// grid (64 b, 2 br), 1024 thr.  Xg layout (round 17, single-wave lstm):
//   Xg[t*16384 + ((bt*64 + lane)*16 + ct)]
//   where bt=b>>2, lane=((b&3)<<4)|(n&15), ct=n>>4  (col n = ct*16 + l16)
__global__ __launch_bounds__(1024) void branch_kernel(const float* __restrict__ S3,
        const float* __restrict__ w_sc0, const float* __restrict__ b_sc0,
        const float* __restrict__ w_ih0, const float* __restrict__ b_ih0, const float* __restrict__ b_hh0,
        const float* __restrict__ w_sc1, const float* __restrict__ b_sc1,
        const float* __restrict__ w_ih1, const float* __restrict__ b_ih1, const float* __restrict__ b_hh1,
        float* __restrict__ Xg0, float* __restrict__ Xg1) {
    const int b = blockIdx.x, br = blockIdx.y;
    const int T = br ? 100 : 300;
    const float* w_sc = br ? w_sc1 : w_sc0;
    const float* b_sc = br ? b_sc1 : b_sc0;
    const float* w_ih = br ? w_ih1 : w_ih0;
    const float* b_ih = br ? b_ih1 : b_ih0;
    const float* b_hh = br ? b_hh1 : b_hh0;
    float* Xg = br ? Xg1 : Xg0;

    __shared__ float bufs[16][2][402];
    __shared__ unsigned short Ps[64][302];   // pooled rows, halo-padded
    __shared__ float xcs[4][304];
    const int tid = threadIdx.x, wv = tid >> 6, lane = tid & 63;

    for (int ci = 0; ci < 4; ++ci) {
        const int c = wv * 4 + ci;
        const float* row = S3 + ((size_t)b * 64 + c) * 802;
        if (br == 0) {
            // bin=300: s=2, k=204 == max over 102 pair-maxes
            float* A = bufs[wv][0];
            float* B = bufs[wv][1];
            for (int it = 0; it < 7; ++it) {
                int q = lane + it * 64;
                if (q < 401) A[q] = fmaxf(row[2 * q], row[2 * q + 1]);
            }
            int len = 401;
#pragma unroll
            for (int sp = 1; sp <= 32; sp <<= 1) {     // doubling -> max of 64
                int nl = len - sp;
                for (int it = 0; it < 7; ++it) {
                    int q = lane + it * 64;
                    if (q < nl) B[q] = fmaxf(A[q], A[q + sp]);
                }
                float* tmp = A; A = B; B = tmp; len = nl;
            }
            for (int it = 0; it < 5; ++it) {           // 102 = [t,t+64)U[t+38,t+102)
                int t = lane + it * 64;
                if (t < 300) Ps[c][1 + t] = f2bf(fmaxf(A[t], A[t + 38]));
            }
            if (lane < 2) Ps[c][lane * 301] = 0;
        } else {
            // bin=100: s=8, k=10 direct
            for (int it = 0; it < 2; ++it) {
                int t = lane + it * 64;
                if (t < 100) {
                    float m = row[8 * t];
#pragma unroll
                    for (int p = 1; p < 10; ++p) m = fmaxf(m, row[8 * t + p]);
                    Ps[c][1 + t] = f2bf(m);
                }
            }
            if (lane < 2) Ps[c][lane * 101] = 0;
        }
    }
    __syncthreads();
    // conv k=3 p=1 + leaky -> xcs LDS
    for (int i = tid; i < 4 * T; i += 1024) {
        int o = i / T, t = i - o * T;
        float sum = b_sc[o];
        const float* wvp = w_sc + o * 192;
        for (int c = 0; c < 64; ++c) {
            float p0 = bf2f(Ps[c][t]), p1 = bf2f(Ps[c][t + 1]), p2 = bf2f(Ps[c][t + 2]);
            sum += wvp[c * 3] * p0 + wvp[c * 3 + 1] * p1 + wvp[c * 3 + 2] * p2;
        }
        xcs[o][t] = leaky(sum);
    }
    __syncthreads();
    // Xg phase: n = tid&255 gate column, tq = tid>>8 time-phase; pre-scaled
    {
        const int n = tid & 255, tq = tid >> 8;
        const int g = n >> 6;
        const float sc = (g == 2) ? (-2.0f * LOG2E) : (-LOG2E);
        const float4 w4 = *(const float4*)(w_ih + n * 4);
        const float bias = b_ih[n] + b_hh[n];
        const size_t off0 = (((size_t)(b >> 2)) * 64
                             + (size_t)(((b & 3) << 4) | (n & 15))) * 16
                            + (size_t)(n >> 4);
        for (int t = tq; t < T; t += 4) {
            float v = bias + w4.x * xcs[0][t] + w4.y * xcs[1][t]
                           + w4.z * xcs[2][t] + w4.w * xcs[3][t];
            Xg[(size_t)t * 16384 + off0] = sc * v;
        }
    }
}

// ---------------------------------------------------------------------------
// lstm (+fused head): grid (16 bt, 2 br), 64 thr = ONE wave.
// The wave computes all 4 gates x 64 hidden x 4 batches itself:
//   A (16x32 bf16): rows = batches at {0,4,8,12} (others garbage -> C rows
//   we never read), built from packed-h via 16 ds_bpermute + shifts.
//   B: 16 col-tiles x 2 k-halves of W_hh (pre-scaled), 128 VGPRs.
//   C: acc[ct], lane reads [0] only: batch=lane>>4, col=ct*16+l16.
// NO barrier / NO LDS / NO waitcnt in the 300-step recurrence.
__global__ __launch_bounds__(64) void lstm_kernel(
    const float* __restrict__ Xg0, const float* __restrict__ Xg1,
    const float* __restrict__ Whh0, const float* __restrict__ Whh1,
    const float* __restrict__ wl0, const float* __restrict__ bl0,
    const float* __restrict__ wl1, const float* __restrict__ bl1,
    float* __restrict__ brbuf, int* __restrict__ cnt,
    const float* __restrict__ w_rul, const float* __restrict__ b_rul,
    float* __restrict__ out) {
    const int bt = blockIdx.x;            // 16 batch tiles of 4
    const int br = blockIdx.y;
    const int T = (br == 0) ? 300 : 100;
    const float* Xg = (br == 0) ? Xg0 : Xg1;
    const float* Whh = (br == 0) ? Whh0 : Whh1;
    const float* wl = (br == 0) ? wl0 : wl1;
    const float* bl = (br == 0) ? bl0 : bl1;
    const float C2L = -2.0f * LOG2E;

    const int lane = threadIdx.x & 63;
    const int quad = lane >> 4, l16 = lane & 15;

    // --- W_hh fragments: 16 col-tiles x 2 k-halves, pre-scaled by gate ---
    bf16x8 Bf[16][2];
#pragma unroll
    for (int ct = 0; ct < 16; ++ct) {
        const float scg = ((ct >> 2) == 2) ? (-2.0f * LOG2E) : (-LOG2E);
        const int n = ct * 16 + l16;
#pragma unroll
        for (int kc = 0; kc < 2; ++kc) {
            const float* src = Whh + n * 64 + kc * 32 + quad * 8;
            float4 v0 = *(const float4*)(src);
            float4 v1 = *(const float4*)(src + 4);
            bf16x8 v;
            v[0] = (short)f2bf(v0.x * scg); v[1] = (short)f2bf(v0.y * scg);
            v[2] = (short)f2bf(v0.z * scg); v[3] = (short)f2bf(v0.w * scg);
            v[4] = (short)f2bf(v1.x * scg); v[5] = (short)f2bf(v1.y * scg);
            v[6] = (short)f2bf(v1.z * scg); v[7] = (short)f2bf(v1.w * scg);
            Bf[ct][kc] = v;
        }
    }

    // --- bpermute byte-indices for the h transpose ---
    // requester lane l (valid when l16%4==0, batch bq=l16>>2) word w needs
    // hh0=quad*8+2w (lo16) and hh0+1 (hi16); holder lane = (bq<<4)|(hh&15),
    // half = lo for quad<2, hi for quad>=2 (same for A1 with P1).
    int idx0[4], idx1[4];
    {
        const int bq = l16 >> 2;
#pragma unroll
        for (int w2 = 0; w2 < 4; ++w2) {
            int m0 = (bq << 4) | ((quad & 1) * 8 + 2 * w2);
            idx0[w2] = m0 * 4;
            idx1[w2] = (m0 + 1) * 4;
        }
    }
    const int sh = (quad < 2) ? 0 : 16;

    uint32 P0 = 0u, P1 = 0u;   // packed h: {h[l16],h[l16+16]}, {h[l16+32],h[l16+48]} of batch quad
    float cst[4] = {0.f, 0.f, 0.f, 0.f};

    const float* xp = Xg + ((size_t)bt * 64 + lane) * 16;
    f32x4 xaA[4], xaB[4];
#pragma unroll
    for (int p = 0; p < 4; ++p) {
        xaA[p] = *(const f32x4*)(xp + p * 4);
        xaB[p] = *(const f32x4*)(xp + 16384 + p * 4);
    }

    const f32x4 z = {0.f, 0.f, 0.f, 0.f};

    auto step = [&](f32x4* xb) {
        // h -> A-fragment transpose (intra-wave, lockstep-safe)
        uint32 a0[4], a1[4];
#pragma unroll
        for (int w2 = 0; w2 < 4; ++w2) {
            uint32 b00 = (uint32)__builtin_amdgcn_ds_bpermute(idx0[w2], (int)P0);
            uint32 b01 = (uint32)__builtin_amdgcn_ds_bpermute(idx1[w2], (int)P0);
            uint32 b10 = (uint32)__builtin_amdgcn_ds_bpermute(idx0[w2], (int)P1);
            uint32 b11 = (uint32)__builtin_amdgcn_ds_bpermute(idx1[w2], (int)P1);
            a0[w2] = ((b00 >> sh) & 0xFFFFu) | ((b01 >> sh) << 16);
            a1[w2] = ((b10 >> sh) & 0xFFFFu) | ((b11 >> sh) << 16);
        }
        u32x4 A0u = (u32x4){a0[0], a0[1], a0[2], a0[3]};
        u32x4 A1u = (u32x4){a1[0], a1[1], a1[2], a1[3]};
        bf16x8 A0 = __builtin_bit_cast(bf16x8, A0u);
        bf16x8 A1 = __builtin_bit_cast(bf16x8, A1u);

        f32x4 acc[16];
#pragma unroll
        for (int ct = 0; ct < 16; ++ct) {
            acc[ct] = __builtin_amdgcn_mfma_f32_16x16x32_bf16(A0, Bf[ct][0], z, 0, 0, 0);
            acc[ct] = __builtin_amdgcn_mfma_f32_16x16x32_bf16(A1, Bf[ct][1], acc[ct], 0, 0, 0);
        }

        float hvv[4];
#pragma unroll
        for (int j = 0; j < 4; ++j) {        // cell: batch=quad, hidden=j*16+l16
            float si = acc[j][0]      + xb[0][j];
            float sf = acc[4 + j][0]  + xb[1][j];
            float sg = acc[8 + j][0]  + xb[2][j];
            float so = acc[12 + j][0] + xb[3][j];
            float iv = rcp2(si);
            float fv = rcp2(sf);
            float gv = 2.0f * rcp2(sg) - 1.0f;
            float ov = rcp2(so);
            float cs = fv * cst[j] + iv * gv;
            cst[j] = cs;
            float th = 2.0f * rcp2(cs * C2L) - 1.0f;
            hvv[j] = ov * th;
        }
        P0 = (uint32)f2bf(hvv[0]) | ((uint32)f2bf(hvv[1]) << 16);
        P1 = (uint32)f2bf(hvv[2]) | ((uint32)f2bf(hvv[3]) << 16);
    };

    for (int t = 0; t < T; t += 2) {   // T even
        step(xaA);
        if (t + 2 < T) {
#pragma unroll
            for (int p = 0; p < 4; ++p)
                xaA[p] = *(const f32x4*)(xp + (size_t)(t + 2) * 16384 + p * 4);
        }
        step(xaB);
        if (t + 3 < T) {
#pragma unroll
            for (int p = 0; p < 4; ++p)
                xaB[p] = *(const f32x4*)(xp + (size_t)(t + 3) * 16384 + p * 4);
        }
    }

    // final linear: lane holds h(T) for batch=quad, hidden {l16,+16,+32,+48}
    {
        float hb0 = bf2f((unsigned short)(P0 & 0xFFFFu));
        float hb1 = bf2f((unsigned short)(P0 >> 16));
        float hb2 = bf2f((unsigned short)(P1 & 0xFFFFu));
        float hb3 = bf2f((unsigned short)(P1 >> 16));
        float part = hb0 * wl[l16] + hb1 * wl[16 + l16]
                   + hb2 * wl[32 + l16] + hb3 * wl[48 + l16];
        part += __shfl_xor(part, 1);
        part += __shfl_xor(part, 2);
        part += __shfl_xor(part, 4);
        part += __shfl_xor(part, 8);
        if (l16 == 0)
            atomicExch(&brbuf[br * 64 + bt * 4 + quad], part + bl[0]);
    }
    __threadfence();
    int old = 0;
    if (threadIdx.x == 0) old = atomicAdd(cnt, 1);
    old = __shfl(old, 0);
    if (old == 31) {                   // last block computes the head
        __threadfence();
        const int tid = threadIdx.x;   // 64 threads = 64 batches
        float v0 = atomicAdd(&brbuf[tid], 0.0f);        // atomic load
        float v1 = atomicAdd(&brbuf[64 + tid], 0.0f);
        float v = w_rul[0] * v0 + w_rul[1] * v1 + b_rul[0];
        out[tid] = sigm(v);
    }
}

// ---------------------------------------------------------------------------
extern "C" void kernel_launch(void* const* d_in, const int* in_sizes, int n_in,
                              void* d_out, int out_size, void* d_ws, size_t ws_size,
                              hipStream_t stream) {
    const float* X     = (const float*)d_in[0];
    const float* w_dw  = (const float*)d_in[1];
    const float* b_dw  = (const float*)d_in[2];
    const float* w_pw  = (const float*)d_in[3];
    const float* b_pw  = (const float*)d_in[4];
    const float* w_c2  = (const float*)d_in[5];
    const float* b_c2  = (const float*)d_in[6];
    const float* w_sc0 = (const float*)d_in[7];
    const float* b_sc0 = (const float*)d_in[8];
    const float* w_ih0 = (const float*)d_in[9];
    const float* b_ih0 = (const float*)d_in[10];
    const float* w_hh0 = (const float*)d_in[11];
    const float* b_hh0 = (const float*)d_in[12];
    const float* w_l0  = (const float*)d_in[13];
    const float* b_l0  = (const float*)d_in[14];
    const float* w_sc1 = (const float*)d_in[15];
    const float* b_sc1 = (const float*)d_in[16];
    const float* w_ih1 = (const float*)d_in[17];
    const float* b_ih1 = (const float*)d_in[18];
    const float* w_hh1 = (const float*)d_in[19];
    const float* b_hh1 = (const float*)d_in[20];
    const float* w_l1  = (const float*)d_in[21];
    const float* b_l1  = (const float*)d_in[22];
    const float* w_rul = (const float*)d_in[23];
    const float* b_rul = (const float*)d_in[24];

    float* ws = (float*)d_ws;
    float* Xg0 = ws;                                           // 4,915,200 f
    float* Xg1 = ws + 4915200;                                 // 1,638,400 f
    unsigned short* S2b = (unsigned short*)(ws + 6553600);     // 64*32*812 sh
    float* S3    = ws + 7385088;                               // 3,284,992 f
    unsigned short* Wp1 = (unsigned short*)(ws + 10670080);    // 15,360 sh
    float* b_eff = ws + 10677760;                              // 32
    float* brbuf = ws + 10677792;                              // 128
    int*   cnt   = (int*)(ws + 10677920);                      // 1  (~42.7 MB)

    prep_kernel<<<16, 256, 0, stream>>>(w_dw, b_dw, w_pw, b_pw, Wp1, b_eff);
    conv1p_kernel<<<dim3(26, 64), 256, 0, stream>>>(X, Wp1, b_eff, S2b, cnt);
    conv2_kernel<<<dim3(13, 64), 256, 0, stream>>>(S2b, w_c2, b_c2, S3);
    branch_kernel<<<dim3(64, 2), 1024, 0, stream>>>(
        S3, w_sc0, b_sc0, w_ih0, b_ih0, b_hh0,
            w_sc1, b_sc1, w_ih1, b_ih1, b_hh1, Xg0, Xg1);
    lstm_kernel<<<dim3(16, 2), 64, 0, stream>>>(Xg0, Xg1, w_hh0, w_hh1,
                                                w_l0, b_l0, w_l1, b_l1,
                                                brbuf, cnt, w_rul, b_rul, (float*)d_out);
}

// Round 9
// 324.595 us; speedup vs baseline: 1.5316x; 1.5316x over previous
//
#include <hip/hip_runtime.h>
#include <cstddef>

// ---------------------------------------------------------------------------
// CNN1D_LSTM1 pipeline, round 18: restore r13 (best known: 329.7us total,
// 96.2us lstm) + fma tanh-tail (the one safe trim from r14's bundle).
//   prep:   conv1 effective-weight pack (bf16 B-fragments) + b_eff
//   conv1p: conv 16->32 k30 MFMA + fused maxpool(k20,s5,ceil) -> S2b bf16
//   conv2:  conv 32->64 k10 MFMA (self-packs weights) -> S3 fp32
//   branch: adaptive maxpool + conv(64->4,k3,p1)+leaky + Xg store
//   lstm:   batch-tile=4, 1 cell/lane, 32 blocks, 4 waves (1/SIMD);
//           per-step fence = ONE asm {s_waitcnt lgkmcnt(0); s_barrier}
//           (no vmcnt drain -> depth-4 Xg ring stays in flight);
//           tail: h = fma(2*ov, rr, -ov) (one fewer serial mul).
// Model (6 experiments): lone-wave wall = per-wave issue + exposed chain;
// r13's 4-wave split of the LDS h-exchange is the constrained optimum —
// every alternative (intra-wave ILP, redundant compute, shared-barrier
// SIMD sharing) raised issue or lockstepped waves and regressed.
// ---------------------------------------------------------------------------

typedef __attribute__((ext_vector_type(8))) short bf16x8;
typedef __attribute__((ext_vector_type(4))) float f32x4;
typedef unsigned int uint32;

#define LOG2E 1.4426950408889634f

__device__ __forceinline__ unsigned short f2bf(float f) {
    unsigned u = __float_as_uint(f);
    u += 0x7fffu + ((u >> 16) & 1u);   // RNE
    return (unsigned short)(u >> 16);
}
__device__ __forceinline__ float bf2f(unsigned short h) {
    return __uint_as_float(((unsigned)h) << 16);
}
__device__ __forceinline__ float exp2_(float x) {
#if __has_builtin(__builtin_amdgcn_exp2f)
    return __builtin_amdgcn_exp2f(x);
#else
    return __expf(0.6931471805599453f * x);
#endif
}
// rcp2(x) = 1/(1+2^x).  With x pre-scaled by -log2e: == sigmoid(a).
__device__ __forceinline__ float rcp2(float x) {
    return __builtin_amdgcn_rcpf(1.0f + exp2_(x));
}
__device__ __forceinline__ float sigm(float x) {
    return __builtin_amdgcn_rcpf(1.0f + __expf(-x));
}
__device__ __forceinline__ float leaky(float v) { return v >= 0.0f ? v : 0.01f * v; }

// ---------------------------------------------------------------------------
// prep: Wp1[(kc*32+n)*32 + k'] = w_eff(ch=k'&15, kappa=2kc+(k'>>4), o=n); b_eff
__global__ void prep_kernel(const float* __restrict__ w_dw, const float* __restrict__ b_dw,
                            const float* __restrict__ w_pw, const float* __restrict__ b_pw,
                            unsigned short* __restrict__ Wp1, float* __restrict__ b_eff) {
    const int bid = blockIdx.x, tid = threadIdx.x;
    if (bid < 15) {
        const int kc = bid;
        for (int it = 0; it < 4; ++it) {
            int idx = tid + it * 256;
            int n = idx >> 5, kp = idx & 31;
            int ch = kp & 15, kappa = kc * 2 + (kp >> 4);
            float s = 0.f;
            for (int j = 0; j < 16; ++j)
                s += w_pw[n * 256 + ch * 16 + j] * w_dw[(ch * 16 + j) * 30 + kappa];
            Wp1[(kc * 32 + n) * 32 + kp] = f2bf(s);
        }
    } else if (tid < 32) {
        float s = b_pw[tid];
        for (int c = 0; c < 256; ++c) s += w_pw[tid * 256 + c] * b_dw[c];
        b_eff[tid] = s;
    }
}

// ---------------------------------------------------------------------------
// conv1p: grid (26 ttiles, 64 b), 256 thr.  Tile = 32 pool outputs.
__global__ __launch_bounds__(256) void conv1p_kernel(const float* __restrict__ X,
        const unsigned short* __restrict__ Wp1, const float* __restrict__ b_eff,
        unsigned short* __restrict__ S2b, int* __restrict__ cnt) {
    const int b = blockIdx.y, tx = blockIdx.x, tid = threadIdx.x;
    if (tx == 0 && b == 0 && tid == 0) *cnt = 0;   // reset lstm completion counter
    const int l0 = tx * 160;
    __shared__ __align__(16) unsigned short Wl[480 * 40];  // B-frags, rows padded
    __shared__ __align__(16) unsigned short U[192 * 33];   // Xt[224*24] then Ct[192*33]
    unsigned short* Xt = U;
    {   // stage weights: 1920 int4 (rows 16 dw -> padded 20, 16B-aligned)
        const int4* s4 = (const int4*)Wp1;
        for (int j = tid; j < 1920; j += 256)
            *(int4*)((uint32*)Wl + (j >> 2) * 20 + (j & 3) * 4) = s4[j];
    }
    // stage X transposed bf16, float4 global loads
    for (int i = tid; i < 896; i += 256) {
        int ch = i / 56, p4 = (i - ch * 56) * 4;
        int l = l0 + p4;
        float4 v = {0.f, 0.f, 0.f, 0.f};
        const float* xrow = X + ((size_t)b * 16 + ch) * 4096;
        if (l + 3 < 4096 && p4 + 3 < 221) {
            v = *(const float4*)(xrow + l);
        } else {
            float* vv = (float*)&v;
#pragma unroll
            for (int e = 0; e < 4; ++e) {
                int p = p4 + e, le = l + e;
                vv[e] = (p < 221 && le < 4096) ? xrow[le] : 0.f;
            }
        }
        unsigned short* dst = Xt + p4 * 24 + ch;
        dst[0] = f2bf(v.x); dst[24] = f2bf(v.y); dst[48] = f2bf(v.z); dst[72] = f2bf(v.w);
    }
    __syncthreads();
    const int w = tid >> 6, lane = tid & 63, quad = lane >> 4, l16 = lane & 15;
    const int ki = quad >> 1, ch0 = (quad & 1) * 8;
    f32x4 acc[3][2];
#pragma unroll
    for (int mi = 0; mi < 3; ++mi)
#pragma unroll
        for (int nt = 0; nt < 2; ++nt) acc[mi][nt] = (f32x4){0.f, 0.f, 0.f, 0.f};
#pragma unroll
    for (int kc = 0; kc < 15; ++kc) {
        bf16x8 B0 = *(const bf16x8*)(Wl + (kc * 32 + l16) * 40 + quad * 8);
        bf16x8 B1 = *(const bf16x8*)(Wl + (kc * 32 + 16 + l16) * 40 + quad * 8);
#pragma unroll
        for (int mi = 0; mi < 3; ++mi) {
            int mrow = (w + mi * 4) * 16 + l16 + 2 * kc + ki;
            bf16x8 A = *(const bf16x8*)(Xt + mrow * 24 + ch0);
            acc[mi][0] = __builtin_amdgcn_mfma_f32_16x16x32_bf16(A, B0, acc[mi][0], 0, 0, 0);
            acc[mi][1] = __builtin_amdgcn_mfma_f32_16x16x32_bf16(A, B1, acc[mi][1], 0, 0, 0);
        }
    }
    __syncthreads();                 // all Xt reads done; reuse U as Ct
    unsigned short* Ct = U;          // [192][33]
#pragma unroll
    for (int mi = 0; mi < 3; ++mi) {
        int lrow = (w + mi * 4) * 16 + quad * 4;
#pragma unroll
        for (int nt = 0; nt < 2; ++nt) {
            int o = nt * 16 + l16;
            float be = b_eff[o];
#pragma unroll
            for (int r = 0; r < 4; ++r)
                Ct[(lrow + r) * 33 + o] = f2bf(leaky(acc[mi][nt][r] + be));
        }
    }
    __syncthreads();
    for (int idx = tid; idx < 1024; idx += 256) {    // 32 t x 32 ch
        int ti = idx >> 5, ch = idx & 31;
        int t = tx * 32 + ti;
        if (t < 811) {
            int pmax = 4067 - 5 * t; if (pmax > 20) pmax = 20;   // ceil_mode clamp
            int pbase = 5 * ti;
            float m = bf2f(Ct[pbase * 33 + ch]);
            for (int p = 1; p < pmax; ++p) m = fmaxf(m, bf2f(Ct[(pbase + p) * 33 + ch]));
            S2b[((size_t)b * 32 + ch) * 812 + t] = f2bf(m);
        }
    }
}

// ---------------------------------------------------------------------------
// conv2: grid (13 ltiles, 64 b).  M=64, N=64, K=320; self-packs weights.
__global__ __launch_bounds__(256) void conv2_kernel(const unsigned short* __restrict__ S2b,
        const float* __restrict__ w_c2, const float* __restrict__ b_c2,
        float* __restrict__ S3) {
    const int b = blockIdx.y, l0 = blockIdx.x * 64, tid = threadIdx.x;
    __shared__ __align__(16) unsigned short At[80 * 40];
    __shared__ __align__(16) unsigned short Wl[10 * 64 * 40];
    for (int pair = tid; pair < 2048; pair += 256) {   // (n, kp=ch) pairs
        int n = pair >> 5, kp = pair & 31;
        const float* src = w_c2 + n * 320 + kp * 10;
        unsigned short* dstc = Wl + n * 40 + kp;
#pragma unroll
        for (int kc = 0; kc < 10; ++kc) dstc[kc * 2560] = f2bf(src[kc]);
    }
    for (int i = tid; i < 2560; i += 256) {
        int ch = i / 80, p = i - ch * 80;
        int l = l0 + p;
        At[p * 40 + ch] = (p < 73 && l < 811)
            ? S2b[((size_t)b * 32 + ch) * 812 + l] : (unsigned short)0;
    }
    __syncthreads();
    const int w = tid >> 6, lane = tid & 63, quad = lane >> 4, l16 = lane & 15;
    const int mA = w * 16 + l16, ch0 = quad * 8;
    f32x4 acc[4];
#pragma unroll
    for (int nt = 0; nt < 4; ++nt) acc[nt] = (f32x4){0.f, 0.f, 0.f, 0.f};
#pragma unroll
    for (int kc = 0; kc < 10; ++kc) {
        bf16x8 A = *(const bf16x8*)(At + (mA + kc) * 40 + ch0);
#pragma unroll
        for (int nt = 0; nt < 4; ++nt) {
            bf16x8 Bf = *(const bf16x8*)(Wl + (kc * 64 + nt * 16 + l16) * 40 + quad * 8);
            acc[nt] = __builtin_amdgcn_mfma_f32_16x16x32_bf16(A, Bf, acc[nt], 0, 0, 0);
        }
    }
    const int lbase = l0 + w * 16 + quad * 4;
#pragma unroll
    for (int nt = 0; nt < 4; ++nt) {
        int o = nt * 16 + l16;
        float bc = b_c2[o];
#pragma unroll
        for (int r = 0; r < 4; ++r) {
            int l = lbase + r;
            if (l < 802) S3[((size_t)b * 64 + o) * 802 + l] = leaky(acc[nt][r] + bc);
        }
    }
}

// ---------------------------------------------------------------------------
// branch: adaptive maxpool + conv(64->4,k3,p1)+leaky + Xg precompute+store.
// grid (64 b, 2 br), 1024 thr.  Xg layout:
//   Xg[t*16384 + (((bt*4+wv)*4 + q)*16 + l16)*4 + g],  bt=b>>2, q=b&3
// so an lstm lane (quad=q, l16) of wave wv reads its 4 gates as one float4.
__global__ __launch_bounds__(1024) void branch_kernel(const float* __restrict__ S3,
        const float* __restrict__ w_sc0, const float* __restrict__ b_sc0,
        const float* __restrict__ w_ih0, const float* __restrict__ b_ih0, const float* __restrict__ b_hh0,
        const float* __restrict__ w_sc1, const float* __restrict__ b_sc1,
        const float* __restrict__ w_ih1, const float* __restrict__ b_ih1, const float* __restrict__ b_hh1,
        float* __restrict__ Xg0, float* __restrict__ Xg1) {
    const int b = blockIdx.x, br = blockIdx.y;
    const int T = br ? 100 : 300;
    const float* w_sc = br ? w_sc1 : w_sc0;
    const float* b_sc = br ? b_sc1 : b_sc0;
    const float* w_ih = br ? w_ih1 : w_ih0;
    const float* b_ih = br ? b_ih1 : b_ih0;
    const float* b_hh = br ? b_hh1 : b_hh0;
    float* Xg = br ? Xg1 : Xg0;

    __shared__ float bufs[16][2][402];
    __shared__ unsigned short Ps[64][302];   // pooled rows, halo-padded
    __shared__ float xcs[4][304];
    const int tid = threadIdx.x, wv = tid >> 6, lane = tid & 63;

    for (int ci = 0; ci < 4; ++ci) {
        const int c = wv * 4 + ci;
        const float* row = S3 + ((size_t)b * 64 + c) * 802;
        if (br == 0) {
            // bin=300: s=2, k=204 == max over 102 pair-maxes
            float* A = bufs[wv][0];
            float* B = bufs[wv][1];
            for (int it = 0; it < 7; ++it) {
                int q = lane + it * 64;
                if (q < 401) A[q] = fmaxf(row[2 * q], row[2 * q + 1]);
            }
            int len = 401;
#pragma unroll
            for (int sp = 1; sp <= 32; sp <<= 1) {     // doubling -> max of 64
                int nl = len - sp;
                for (int it = 0; it < 7; ++it) {
                    int q = lane + it * 64;
                    if (q < nl) B[q] = fmaxf(A[q], A[q + sp]);
                }
                float* tmp = A; A = B; B = tmp; len = nl;
            }
            for (int it = 0; it < 5; ++it) {           // 102 = [t,t+64)U[t+38,t+102)
                int t = lane + it * 64;
                if (t < 300) Ps[c][1 + t] = f2bf(fmaxf(A[t], A[t + 38]));
            }
            if (lane < 2) Ps[c][lane * 301] = 0;
        } else {
            // bin=100: s=8, k=10 direct
            for (int it = 0; it < 2; ++it) {
                int t = lane + it * 64;
                if (t < 100) {
                    float m = row[8 * t];
#pragma unroll
                    for (int p = 1; p < 10; ++p) m = fmaxf(m, row[8 * t + p]);
                    Ps[c][1 + t] = f2bf(m);
                }
            }
            if (lane < 2) Ps[c][lane * 101] = 0;
        }
    }
    __syncthreads();
    // conv k=3 p=1 + leaky -> xcs LDS
    for (int i = tid; i < 4 * T; i += 1024) {
        int o = i / T, t = i - o * T;
        float sum = b_sc[o];
        const float* wvp = w_sc + o * 192;
        for (int c = 0; c < 64; ++c) {
            float p0 = bf2f(Ps[c][t]), p1 = bf2f(Ps[c][t + 1]), p2 = bf2f(Ps[c][t + 2]);
            sum += wvp[c * 3] * p0 + wvp[c * 3 + 1] * p1 + wvp[c * 3 + 2] * p2;
        }
        xcs[o][t] = leaky(sum);
    }
    __syncthreads();
    // Xg phase: n = tid&255 gate column, tq = tid>>8 time-phase; pre-scaled
    {
        const int n = tid & 255, tq = tid >> 8;
        const int g = n >> 6;
        const float sc = (g == 2) ? (-2.0f * LOG2E) : (-LOG2E);
        const float4 w4 = *(const float4*)(w_ih + n * 4);
        const float bias = b_ih[n] + b_hh[n];
        const int bt = b >> 2, q = b & 3;
        const int hidx = n & 63;
        const int wv2 = hidx >> 4, l16 = hidx & 15;
        const size_t off0 = ((((size_t)bt * 4 + wv2) * 4 + q) * 16 + l16) * 4 + g;
        for (int t = tq; t < T; t += 4) {
            float v = bias + w4.x * xcs[0][t] + w4.y * xcs[1][t]
                           + w4.z * xcs[2][t] + w4.w * xcs[3][t];
            Xg[(size_t)t * 16384 + off0] = sc * v;
        }
    }
}

// ---------------------------------------------------------------------------
// lstm (+fused head): grid (16 bt, 2 br), 256 thr, 1 wave/SIMD.
// Batch tile = 4, placed at MFMA rows {0,4,8,12} (r=0 of each quad):
// one activation cell per lane.  Per-step fence: ONE inline asm
// {s_waitcnt lgkmcnt(0); s_barrier} with "memory" clobber (no vmcnt drain,
// no LDS op can cross).  Tail: h = fma(2*ov, rr, -ov).
#define HPAD 72
__global__ __launch_bounds__(256) void lstm_kernel(
    const float* __restrict__ Xg0, const float* __restrict__ Xg1,
    const float* __restrict__ Whh0, const float* __restrict__ Whh1,
    const float* __restrict__ wl0, const float* __restrict__ bl0,
    const float* __restrict__ wl1, const float* __restrict__ bl1,
    float* __restrict__ brbuf, int* __restrict__ cnt,
    const float* __restrict__ w_rul, const float* __restrict__ b_rul,
    float* __restrict__ out) {
    const int bt = blockIdx.x;            // 16 batch tiles of 4
    const int br = blockIdx.y;
    const int T = (br == 0) ? 300 : 100;
    const float* Xg = (br == 0) ? Xg0 : Xg1;
    const float* Whh = (br == 0) ? Whh0 : Whh1;
    const float* wl = (br == 0) ? wl0 : wl1;
    const float* bl = (br == 0) ? bl0 : bl1;
    const float C2L = -2.0f * LOG2E;

    __shared__ __align__(16) unsigned short h_lds[2][16][HPAD];
    __shared__ int lastf;

    const int tid = threadIdx.x;
    const int w = tid >> 6, lane = tid & 63, quad = lane >> 4, l16 = lane & 15;
    const int hidx = w * 16 + l16;

    bf16x8 Bf[4][2];
#pragma unroll
    for (int g = 0; g < 4; ++g) {
        const int n = g * 64 + hidx;
        const float scg = (g == 2) ? (-2.0f * LOG2E) : (-LOG2E);
#pragma unroll
        for (int kc = 0; kc < 2; ++kc) {
            const float* src = Whh + n * 64 + kc * 32 + quad * 8;
            bf16x8 v;
#pragma unroll
            for (int j = 0; j < 8; ++j) v[j] = (short)f2bf(src[j] * scg);
            Bf[g][kc] = v;
        }
    }

    // zero BOTH h buffers: only rows {0,4,8,12} are ever written, the rest
    // must stay zero so dead A-rows contribute exactly 0.
    for (int i = tid; i < 2 * 16 * HPAD; i += 256) (&h_lds[0][0][0])[i] = 0;

    // per-lane gate slot: batch bt*4+quad, hidden hidx, gates g=0..3 contiguous
    const float* xp = Xg + (((size_t)bt * 4 + w) * 4 + quad) * 64 + l16 * 4;

    f32x4 xq[4];
#pragma unroll
    for (int j = 0; j < 4; ++j) xq[j] = *(const f32x4*)(xp + (size_t)j * 16384);

    float c0 = 0.f;

    __syncthreads();   // once: h_lds zero-init visible (full drain OK here)

    auto step = [&](int t, f32x4& xb) {
        const unsigned short* hrow = &h_lds[t & 1][l16][0];
        bf16x8 A0 = *(const bf16x8*)(hrow + quad * 8);
        bf16x8 A1 = *(const bf16x8*)(hrow + 32 + quad * 8);
        const f32x4 z = {0.f, 0.f, 0.f, 0.f};
        f32x4 ac[4];
#pragma unroll
        for (int g = 0; g < 4; ++g) {
            ac[g] = __builtin_amdgcn_mfma_f32_16x16x32_bf16(A0, Bf[g][0], z, 0, 0, 0);
            ac[g] = __builtin_amdgcn_mfma_f32_16x16x32_bf16(A1, Bf[g][1], ac[g], 0, 0, 0);
        }
        float iv = rcp2(ac[0][0] + xb[0]);                 // sigm(i)
        float fv = rcp2(ac[1][0] + xb[1]);                 // sigm(f)
        float gv = 2.0f * rcp2(ac[2][0] + xb[2]) - 1.0f;   // tanh(g)
        float ov = rcp2(ac[3][0] + xb[3]);                 // sigm(o)
        if (t + 4 < T) xb = *(const f32x4*)(xp + (size_t)(t + 4) * 16384);
        float cs = fv * c0 + iv * gv;
        c0 = cs;
        float rr = __builtin_amdgcn_rcpf(1.0f + exp2_(cs * C2L));
        float hv = fmaf(2.0f * ov, rr, -ov);               // ov*tanh(c), 1 op less
        h_lds[(t + 1) & 1][quad * 4][hidx] = f2bf(hv);
        // LDS-only fence + barrier in ONE asm (memory clobber: no LDS op can
        // cross; no vmcnt drain so the Xg ring stays in flight).
        asm volatile("s_waitcnt lgkmcnt(0)\n\ts_barrier" ::: "memory");
    };

    for (int t = 0; t < T; t += 4) {   // T % 4 == 0
#pragma unroll
        for (int j = 0; j < 4; ++j) step(t + j, xq[j]);
    }

    __syncthreads();   // full barrier once before the head

    // final linear -> brbuf (device-scope atomic stores); batch q at row 4q
    if (tid < 4) {
        const unsigned short* hrow = &h_lds[0][tid * 4][0];
        float s = bl[0];
        for (int j = 0; j < 64; ++j) s += bf2f(hrow[j]) * wl[j];
        atomicExch(&brbuf[br * 64 + bt * 4 + tid], s);
    }
    __syncthreads();
    __threadfence();
    if (tid == 0) {
        int old = atomicAdd(cnt, 1);
        lastf = (old == 31);
    }
    __syncthreads();
    if (lastf) {                       // last block computes the head
        __threadfence();
        if (tid < 64) {
            float v0 = atomicAdd(&brbuf[tid], 0.0f);        // atomic load
            float v1 = atomicAdd(&brbuf[64 + tid], 0.0f);
            float v = w_rul[0] * v0 + w_rul[1] * v1 + b_rul[0];
            out[tid] = sigm(v);
        }
    }
}

// ---------------------------------------------------------------------------
extern "C" void kernel_launch(void* const* d_in, const int* in_sizes, int n_in,
                              void* d_out, int out_size, void* d_ws, size_t ws_size,
                              hipStream_t stream) {
    const float* X     = (const float*)d_in[0];
    const float* w_dw  = (const float*)d_in[1];
    const float* b_dw  = (const float*)d_in[2];
    const float* w_pw  = (const float*)d_in[3];
    const float* b_pw  = (const float*)d_in[4];
    const float* w_c2  = (const float*)d_in[5];
    const float* b_c2  = (const float*)d_in[6];
    const float* w_sc0 = (const float*)d_in[7];
    const float* b_sc0 = (const float*)d_in[8];
    const float* w_ih0 = (const float*)d_in[9];
    const float* b_ih0 = (const float*)d_in[10];
    const float* w_hh0 = (const float*)d_in[11];
    const float* b_hh0 = (const float*)d_in[12];
    const float* w_l0  = (const float*)d_in[13];
    const float* b_l0  = (const float*)d_in[14];
    const float* w_sc1 = (const float*)d_in[15];
    const float* b_sc1 = (const float*)d_in[16];
    const float* w_ih1 = (const float*)d_in[17];
    const float* b_ih1 = (const float*)d_in[18];
    const float* w_hh1 = (const float*)d_in[19];
    const float* b_hh1 = (const float*)d_in[20];
    const float* w_l1  = (const float*)d_in[21];
    const float* b_l1  = (const float*)d_in[22];
    const float* w_rul = (const float*)d_in[23];
    const float* b_rul = (const float*)d_in[24];

    float* ws = (float*)d_ws;
    float* Xg0 = ws;                                           // 4,915,200 f
    float* Xg1 = ws + 4915200;                                 // 1,638,400 f
    unsigned short* S2b = (unsigned short*)(ws + 6553600);     // 64*32*812 sh
    float* S3    = ws + 7385088;                               // 3,284,992 f
    unsigned short* Wp1 = (unsigned short*)(ws + 10670080);    // 15,360 sh
    float* b_eff = ws + 10677760;                              // 32
    float* brbuf = ws + 10677792;                              // 128
    int*   cnt   = (int*)(ws + 10677920);                      // 1  (~42.7 MB)

    prep_kernel<<<16, 256, 0, stream>>>(w_dw, b_dw, w_pw, b_pw, Wp1, b_eff);
    conv1p_kernel<<<dim3(26, 64), 256, 0, stream>>>(X, Wp1, b_eff, S2b, cnt);
    conv2_kernel<<<dim3(13, 64), 256, 0, stream>>>(S2b, w_c2, b_c2, S3);
    branch_kernel<<<dim3(64, 2), 1024, 0, stream>>>(
        S3, w_sc0, b_sc0, w_ih0, b_ih0, b_hh0,
            w_sc1, b_sc1, w_ih1, b_ih1, b_hh1, Xg0, Xg1);
    lstm_kernel<<<dim3(16, 2), 256, 0, stream>>>(Xg0, Xg1, w_hh0, w_hh1,
                                                 w_l0, b_l0, w_l1, b_l1,
                                                 brbuf, cnt, w_rul, b_rul, (float*)d_out);
}